// Round 2
// baseline (178.939 us; speedup 1.0000x reference)
//
#include <hip/hip_runtime.h>

// C[b,i,j,k,l,x,y,z] = sum_{mnop} A[b,m,i,v] A[b,n,j,v] A[b,o,k,v] A[b,p,l,v] C0[m,n,o,p]
// One thread per voxel v (and batch b). Staged contraction, i outermost to
// keep live registers ~60. All loops unrolled -> no scratch.

#define GRID 64
#define NVOX (GRID * GRID * GRID)   // 262144 = 2^18
#define NB 2

__global__ __launch_bounds__(256) void alphaC0_kernel(
    const float* __restrict__ a,    // (B,3,3,G,G,G)
    const float* __restrict__ c0,   // (3,3,3,3)
    float* __restrict__ out)        // (B,3,3,3,3,G,G,G)
{
    const int t = blockIdx.x * blockDim.x + threadIdx.x;  // [0, NB*NVOX)
    const int b = t >> 18;
    const int v = t & (NVOX - 1);

    // Load the 3x3 alpha matrix for this voxel: A[m][i]
    const float* __restrict__ ab = a + (size_t)b * 9 * NVOX + v;
    float A[3][3];
#pragma unroll
    for (int m = 0; m < 3; ++m)
#pragma unroll
        for (int i = 0; i < 3; ++i)
            A[m][i] = ab[(m * 3 + i) * NVOX];

    float* __restrict__ ob = out + (size_t)b * 81 * NVOX + v;

#pragma unroll
    for (int i = 0; i < 3; ++i) {
        // Stage 1: t1[n][o][p] = sum_m A[m][i] * C0[m][n][o][p]   (81 FMA)
        float t1[3][3][3];
#pragma unroll
        for (int n = 0; n < 3; ++n)
#pragma unroll
            for (int o = 0; o < 3; ++o)
#pragma unroll
                for (int p = 0; p < 3; ++p) {
                    float s;
                    s = A[0][i] * c0[((0 * 3 + n) * 3 + o) * 3 + p];
                    s = fmaf(A[1][i], c0[((1 * 3 + n) * 3 + o) * 3 + p], s);
                    s = fmaf(A[2][i], c0[((2 * 3 + n) * 3 + o) * 3 + p], s);
                    t1[n][o][p] = s;
                }

#pragma unroll
        for (int j = 0; j < 3; ++j) {
            // Stage 2: t2[o][p] = sum_n A[n][j] * t1[n][o][p]     (27 FMA)
            float t2[3][3];
#pragma unroll
            for (int o = 0; o < 3; ++o)
#pragma unroll
                for (int p = 0; p < 3; ++p) {
                    float s;
                    s = A[0][j] * t1[0][o][p];
                    s = fmaf(A[1][j], t1[1][o][p], s);
                    s = fmaf(A[2][j], t1[2][o][p], s);
                    t2[o][p] = s;
                }

#pragma unroll
            for (int k = 0; k < 3; ++k) {
                // Stage 3: t3[p] = sum_o A[o][k] * t2[o][p]       (9 FMA)
                float t3[3];
#pragma unroll
                for (int p = 0; p < 3; ++p) {
                    float s;
                    s = A[0][k] * t2[0][p];
                    s = fmaf(A[1][k], t2[1][p], s);
                    s = fmaf(A[2][k], t2[2][p], s);
                    t3[p] = s;
                }

#pragma unroll
                for (int l = 0; l < 3; ++l) {
                    // Stage 4: C = sum_p A[p][l] * t3[p]          (3 FMA)
                    float s;
                    s = A[0][l] * t3[0];
                    s = fmaf(A[1][l], t3[1], s);
                    s = fmaf(A[2][l], t3[2], s);
                    ob[(((i * 3 + j) * 3 + k) * 3 + l) * NVOX] = s;
                }
            }
        }
    }
}

extern "C" void kernel_launch(void* const* d_in, const int* in_sizes, int n_in,
                              void* d_out, int out_size, void* d_ws, size_t ws_size,
                              hipStream_t stream) {
    const float* a  = (const float*)d_in[0];   // (2,3,3,64,64,64) fp32
    const float* c0 = (const float*)d_in[1];   // (3,3,3,3) fp32
    float* out = (float*)d_out;                // (2,81,64^3) fp32

    const int total = NB * NVOX;               // 524288
    const int block = 256;
    const int grid = total / block;            // 2048
    alphaC0_kernel<<<grid, block, 0, stream>>>(a, c0, out);
}